// Round 10
// baseline (194.975 us; speedup 1.0000x reference)
//
#include <hip/hip_runtime.h>
#include <hip/hip_bf16.h>
#include <hip/hip_fp16.h>

#define N_NODES 50000
#define N_EDGES 640000
#define E_TOT   690000   // edges + self-loops
#define CH      128
#define ROWPAD  50176    // padded rows for H/AS/AD/X2 (128-row GEMM tiles overrun)
#define GEMMB   391      // ceil(50000 / 128) row-tiles of 128
#define EBLK    2048     // edges per scatter block
#define NEB     337      // ceil(E_TOT / EBLK)
#define NBUCK   196      // ceil(N_NODES / 256)
#define CAP     4608     // ebuf bucket capacity (mean 3533, sigma 57)
#define CAPC    6144     // csr bucket capacity (edges + 256 nodes x 7 align pad)

typedef __attribute__((ext_vector_type(8))) short short8;
typedef __attribute__((ext_vector_type(4))) float float4v;

static __device__ __forceinline__ float bf2f(unsigned short u) {
  return __uint_as_float(((unsigned)u) << 16);
}
static __device__ __forceinline__ unsigned short f2bf(float f) {
  unsigned u = __float_as_uint(f);
  return (unsigned short)((u + 0x7fffu + ((u >> 16) & 1u)) >> 16);
}

static __device__ __forceinline__ void load_edge(const int* __restrict__ ei,
                                                 int e, int i64, int& s, int& d)
{
  if (e >= N_EDGES) { s = d = e - N_EDGES; return; }
  if (i64) { s = ei[2 * (size_t)e]; d = ei[2 * ((size_t)N_EDGES + e)]; }
  else     { s = ei[e];             d = ei[N_EDGES + e]; }
}

static __device__ __forceinline__ short8 load_bf8(const void* __restrict__ X,
                                                  size_t off, int f32)
{
  if (!f32) return *(const short8*)((const unsigned short*)X + off);
  const float4* p = (const float4*)((const float*)X + off);
  float4 u = p[0], v = p[1];
  short8 r;
  r[0] = (short)f2bf(u.x); r[1] = (short)f2bf(u.y);
  r[2] = (short)f2bf(u.z); r[3] = (short)f2bf(u.w);
  r[4] = (short)f2bf(v.x); r[5] = (short)f2bf(v.y);
  r[6] = (short)f2bf(v.z); r[7] = (short)f2bf(v.w);
  return r;
}

// ---- prep: fused dtype-detect + W transpose + Ba + gcur init -----------
__global__ __launch_bounds__(256) void k_prep(
    const void* __restrict__ W1, const void* __restrict__ W2,
    const void* __restrict__ as1, const void* __restrict__ ad1,
    const void* __restrict__ as2, const void* __restrict__ ad2,
    unsigned short* __restrict__ Wt1, unsigned short* __restrict__ Wt2,
    unsigned short* __restrict__ Ba1, unsigned short* __restrict__ Ba2,
    const unsigned short* __restrict__ x16,
    const unsigned int* __restrict__ eiw,
    int* __restrict__ flags, int* __restrict__ gcur)
{
  int b = blockIdx.x, t = threadIdx.x;
  __shared__ int sf, si;
  if (t == 0) { sf = 0; si = 1; }
  __syncthreads();
  int bad = 0;
  for (int i = t; i < 4096; i += 256) {
    float v = bf2f(x16[i]);
    if (!(v == v) || fabsf(v) > 100.f) bad = 1;
  }
  if (bad) atomicOr(&sf, 1);
  if (b == 0 && t < 128 && eiw[2 * t + 1] != 0u) atomicAnd(&si, 0);
  __syncthreads();
  int f32 = sf;
  if (b == 0 && t == 0) { flags[0] = sf; flags[1] = si; }
  if (b == 0 && t < NBUCK) gcur[t] = t * CAP;   // re-init every launch

  if (b < 8) {
    int g = b * 256 + t;          // 0..2047
    int l = g >> 10;
    int rem = g & 1023;
    int k = rem >> 3, n = rem & 7;
    const void* W  = l ? W2 : W1;
    const void* av = (n < 4) ? (l ? as2 : as1) : (l ? ad2 : ad1);
    int h = n & 3;
    float sum = 0.f;
    for (int c = 0; c < 32; c++) {
      float w = f32 ? ((const float*)W)[k * 128 + h * 32 + c]
                    : bf2f(((const unsigned short*)W)[k * 128 + h * 32 + c]);
      float a = f32 ? ((const float*)av)[h * 32 + c]
                    : bf2f(((const unsigned short*)av)[h * 32 + c]);
      sum += w * a;
    }
    unsigned short* Ba = l ? Ba2 : Ba1;
    Ba[n * 128 + k] = f2bf(sum);
    Ba[(8 + (rem >> 7)) * 128 + (rem & 127)] = 0;   // zero rows 8..15
  } else {
    int b2 = b - 8;
    int l = b2 >> 7, c = b2 & 127;
    if (t < 128) {
      const void* W = l ? W2 : W1;
      unsigned short* Wt = l ? Wt2 : Wt1;
      Wt[c * 128 + t] = f32 ? f2bf(((const float*)W)[t * 128 + c])
                            : ((const unsigned short*)W)[t * 128 + c];
    }
  }
}

// ---- shared GEMM body: 128-row tiles, each B-frag feeds 2 MFMAs ---------
struct SmemG { unsigned short WB[144][136]; };

static __device__ __forceinline__ void gemm_body(
    SmemG& sm, int bx,
    const void* __restrict__ X,
    const unsigned short* __restrict__ Wt_g,
    const unsigned short* __restrict__ Ba_g,
    unsigned short* __restrict__ H, float* __restrict__ AS,
    float* __restrict__ AD, int nrows, int xf32)
{
  int tid = threadIdx.x;
#pragma unroll
  for (int i = 0; i < 8; i++) {
    int j = i * 256 + tid;        // 2048 16B chunks of W^T
    int c = j >> 4, k8 = j & 15;
    *(short8*)&sm.WB[c][k8 * 8] = *(const short8*)(Wt_g + c * 128 + k8 * 8);
  }
  {
    int n = tid >> 4, k8 = tid & 15;   // Ba rows 128..143 (8..15 zeroed)
    *(short8*)&sm.WB[128 + n][k8 * 8] = *(const short8*)(Ba_g + n * 128 + k8 * 8);
  }
  __syncthreads();
  int wave = tid >> 6, lane = tid & 63;
  int R0 = (bx * 4 + wave) * 32;
  if (R0 >= nrows) return;
  int m = lane & 15, quad = lane >> 4;
  int rA = R0 + m;        if (rA >= nrows) rA = nrows - 1;   // clamp: last tile only
  int rB = R0 + 16 + m;   if (rB >= nrows) rB = nrows - 1;
  size_t aA = (size_t)rA * CH + quad * 8;
  size_t aB = (size_t)rB * CH + quad * 8;
  float4v acc[2][8];
  float4v accA[2];
#pragma unroll
  for (int hf = 0; hf < 2; hf++) {
    accA[hf] = (float4v){0.f, 0.f, 0.f, 0.f};
#pragma unroll
    for (int ct = 0; ct < 8; ct++) acc[hf][ct] = (float4v){0.f, 0.f, 0.f, 0.f};
  }
#pragma unroll
  for (int kb = 0; kb < 4; kb++) {
    short8 a0 = load_bf8(X, aA + kb * 32, xf32);
    short8 a1 = load_bf8(X, aB + kb * 32, xf32);
#pragma unroll
    for (int ct = 0; ct < 8; ct++) {
      short8 bb = *(const short8*)&sm.WB[ct * 16 + m][kb * 32 + quad * 8];
      acc[0][ct] = __builtin_amdgcn_mfma_f32_16x16x32_bf16(a0, bb, acc[0][ct], 0, 0, 0);
      acc[1][ct] = __builtin_amdgcn_mfma_f32_16x16x32_bf16(a1, bb, acc[1][ct], 0, 0, 0);
    }
    short8 bA = *(const short8*)&sm.WB[128 + m][kb * 32 + quad * 8];
    accA[0] = __builtin_amdgcn_mfma_f32_16x16x32_bf16(a0, bA, accA[0], 0, 0, 0);
    accA[1] = __builtin_amdgcn_mfma_f32_16x16x32_bf16(a1, bA, accA[1], 0, 0, 0);
  }
#pragma unroll
  for (int hf = 0; hf < 2; hf++) {
    int rbase = R0 + hf * 16 + quad * 4;
#pragma unroll
    for (int ct = 0; ct < 8; ct++) {
      int col = ct * 16 + m;
#pragma unroll
      for (int r = 0; r < 4; r++)
        H[(size_t)(rbase + r) * CH + col] = __half_as_ushort(__float2half(acc[hf][ct][r]));
    }
    if (m < 4) {
#pragma unroll
      for (int r = 0; r < 4; r++)
        AS[(size_t)(rbase + r) * 4 + m] = accA[hf][r];
    } else if (m < 8) {
#pragma unroll
      for (int r = 0; r < 4; r++)
        AD[(size_t)(rbase + r) * 4 + (m - 4)] = accA[hf][r];
    }
  }
}

// layer-2 GEMM (standalone; X2 always bf16)
__global__ __launch_bounds__(256, 2) void k_gemm(
    const void* __restrict__ X,
    const unsigned short* __restrict__ Wt_g,
    const unsigned short* __restrict__ Ba_g,
    unsigned short* __restrict__ H, float* __restrict__ AS, float* __restrict__ AD,
    int nrows)
{
  __shared__ SmemG sm;
  gemm_body(sm, blockIdx.x, X, Wt_g, Ba_g, H, AS, AD, nrows, 0);
}

// layer-1 GEMM fused with block-local counting-sort scatter.
// (round-1 lesson: per-node global cursors = 15x write amplification from
// cross-XCD line bouncing; ~10-edge contiguous chunks avoid that.)
__global__ __launch_bounds__(256, 2) void k_gemm_scat(
    const void* __restrict__ X,
    const unsigned short* __restrict__ Wt_g,
    const unsigned short* __restrict__ Ba_g,
    unsigned short* __restrict__ H, float* __restrict__ AS, float* __restrict__ AD,
    int nrows, const int* __restrict__ ei, int* __restrict__ gcur,
    unsigned int* __restrict__ ebuf, const int* __restrict__ flags)
{
  __shared__ SmemG sm;          // gemm blocks only
  __shared__ int hist[NBUCK];   // scatter blocks only
  __shared__ int cur[NBUCK];
  if (blockIdx.x >= GEMMB) {
    int b = blockIdx.x - GEMMB;
    int t = threadIdx.x;
    if (t < NBUCK) hist[t] = 0;
    __syncthreads();
    int i64 = flags[1];
    int base = b * EBLK;
    int sA[8], dA[8];
#pragma unroll
    for (int k = 0; k < 8; k++) {
      int e = base + k * 256 + t;
      sA[k] = -1;
      if (e < E_TOT) {
        load_edge(ei, e, i64, sA[k], dA[k]);
        atomicAdd(&hist[dA[k] >> 8], 1);
      }
    }
    __syncthreads();
    if (t < NBUCK) {
      int c = hist[t];
      cur[t] = c ? atomicAdd(&gcur[t], c) : 0;   // reserve contiguous chunk
    }
    __syncthreads();
#pragma unroll
    for (int k = 0; k < 8; k++) {
      if (sA[k] >= 0) {
        int pos = atomicAdd(&cur[dA[k] >> 8], 1);   // LDS atomic
        ebuf[pos] = ((unsigned)sA[k] << 8) | (unsigned)(dA[k] & 255);
      }
    }
    return;
  }
  gemm_body(sm, blockIdx.x, X, Wt_g, Ba_g, H, AS, AD, nrows, flags[0]);
}

// per-bucket fine CSR -> rpdeg (int2) + ushort csr.
// 8-entry-aligned segments so k_agg fetches 8 indices with one short8;
// only the pad slots are zeroed (<=7/node) — agg reads stay inside segments.
__global__ __launch_bounds__(256) void k_fine(
    const unsigned int* __restrict__ ebuf, const int* __restrict__ gcur,
    int2* __restrict__ rpdeg, unsigned short* __restrict__ csr)
{
  __shared__ int cnt[256], sh[256], cur[256];
  int q = blockIdx.x, t = threadIdx.x;
  int lo = q * CAP, hi = gcur[q];
  int lc = q * CAPC;
  cnt[t] = 0;
  __syncthreads();
  for (int i = lo + t; i < hi; i += 256)
    atomicAdd(&cnt[ebuf[i] & 255u], 1);
  __syncthreads();
  int v = cnt[t];
  int a = (v + 7) & ~7;          // 8-aligned segment size
  sh[t] = a;
  __syncthreads();
  for (int off = 1; off < 256; off <<= 1) {
    int u = (t >= off) ? sh[t - off] : 0;
    __syncthreads();
    sh[t] += u;
    __syncthreads();
  }
  int lpa = sh[t] - a;           // exclusive aligned prefix
  int n = (q << 8) + t;
  if (n < N_NODES) rpdeg[n] = make_int2(lc + lpa, v);
  cur[t] = lc + lpa;
  for (int i = v; i < a; i++) csr[lc + lpa + i] = 0;   // zero pad slots only
  __syncthreads();
  for (int i = lo + t; i < hi; i += 256) {
    unsigned p = ebuf[i];
    int slot = atomicAdd(&cur[p & 255u], 1);   // LDS atomic
    csr[slot] = (unsigned short)(p >> 8);
  }
}

// ---- fused gather-aggregate + softmax + epilogue ------------------------
// two nodes per wave (32 lanes/node, 4 ch/lane); one short8 csr load per
// 8-edge round, software-pipelined: round r+1's csr load issues before
// round r's gathers, removing the csr L2 latency from the serial chain.
// __launch_bounds__(256, 8) keeps allocator <=64 VGPR (8 waves/SIMD).
__global__ __launch_bounds__(256, 8) void k_agg(
    const int2* __restrict__ rpdeg,
    const unsigned short* __restrict__ csr,
    const unsigned short* __restrict__ H,
    const float* __restrict__ AS, const float* __restrict__ AD,
    const void* __restrict__ b, void* __restrict__ Y,
    const int* __restrict__ flags, int layer)
{
  int tid = threadIdx.x;
  int node = blockIdx.x * 8 + (tid >> 5);
  if (node >= N_NODES) return;
  int lane = tid & 31;
  int h = lane >> 3;          // 4 channels/lane
  int c0 = 4 * lane;
  int2 rd = rpdeg[node];
  int start = rd.x, dg = rd.y;
  float adh = AD[node * 4 + h];
  float acc0 = 0.f, acc1 = 0.f, acc2 = 0.f, acc3 = 0.f, den = 0.f;
  int nr = (dg + 7) >> 3;                          // rounds (dg >= 1)
  short8 sv = *(const short8*)(csr + start);       // preload round 0
  for (int r = 0; r < nr; r++) {
    int jn = (r + 1 < nr) ? (r + 1) * 8 : r * 8;   // clamp: dup last (in-bounds)
    short8 svn = *(const short8*)(csr + start + jn);   // prefetch next round
    int j = r * 8;
    int sI[8];
#pragma unroll
    for (int u = 0; u < 8; u++) sI[u] = ((int)sv[u]) & 0xFFFF;
    float2 vR[8];
#pragma unroll
    for (int u = 0; u < 8; u++)
      vR[u] = *(const float2*)(H + (sI[u] << 7) + c0);   // 4 halves, 8B
    float eV[8];
#pragma unroll
    for (int u = 0; u < 8; u++)
      eV[u] = AS[(sI[u] << 2) + h] + adh;
#pragma unroll
    for (int u = 0; u < 8; u++) {
      float x = eV[u];
      x = fmaxf(x, 0.2f * x);                  // leaky_relu(0.2)
      float ex = (j + u < dg) ? __expf(x) : 0.f;
      __half2 p0 = __builtin_bit_cast(__half2, vR[u].x);
      __half2 p1 = __builtin_bit_cast(__half2, vR[u].y);
      float2 f0 = __half22float2(p0);
      float2 f1 = __half22float2(p1);
      acc0 += ex * f0.x;
      acc1 += ex * f0.y;
      acc2 += ex * f1.x;
      acc3 += ex * f1.y;
      den  += ex;
    }
    sv = svn;
  }
  float inv = 1.f / (den + 1e-16f);
  int f32 = flags[0];
  float b0, b1, b2, b3;
  if (f32) {
    const float* bp = (const float*)b;
    b0 = bp[c0]; b1 = bp[c0 + 1]; b2 = bp[c0 + 2]; b3 = bp[c0 + 3];
  } else {
    const unsigned short* bp = (const unsigned short*)b;
    b0 = bf2f(bp[c0]); b1 = bf2f(bp[c0 + 1]);
    b2 = bf2f(bp[c0 + 2]); b3 = bf2f(bp[c0 + 3]);
  }
  float r0 = acc0 * inv + b0;
  float r1 = acc1 * inv + b1;
  float r2 = acc2 * inv + b2;
  float r3 = acc3 * inv + b3;
  int o = node * CH + c0;
  if (layer == 1) {                 // relu + bf16 -> X2
    r0 = r0 > 0.f ? r0 : 0.f;  r1 = r1 > 0.f ? r1 : 0.f;
    r2 = r2 > 0.f ? r2 : 0.f;  r3 = r3 > 0.f ? r3 : 0.f;
    ushort4 w;
    w.x = f2bf(r0); w.y = f2bf(r1); w.z = f2bf(r2); w.w = f2bf(r3);
    *(ushort4*)((unsigned short*)Y + o) = w;
  } else if (f32) {
    float4 w; w.x = r0; w.y = r1; w.z = r2; w.w = r3;
    *(float4*)((float*)Y + o) = w;
  } else {
    ushort4 w;
    w.x = f2bf(r0); w.y = f2bf(r1); w.z = f2bf(r2); w.w = f2bf(r3);
    *(ushort4*)((unsigned short*)Y + o) = w;
  }
}

extern "C" void kernel_launch(void* const* d_in, const int* in_sizes, int n_in,
                              void* d_out, int out_size, void* d_ws, size_t ws_size,
                              hipStream_t stream)
{
  const void* x   = d_in[0];
  const int*  ei  = (const int*)d_in[1];
  const void* W1  = d_in[2];
  const void* as1 = d_in[3];
  const void* ad1 = d_in[4];
  const void* b1  = d_in[5];
  const void* W2  = d_in[6];
  const void* as2 = d_in[7];
  const void* ad2 = d_in[8];
  const void* b2  = d_in[9];

  char* ws = (char*)d_ws;
  unsigned short* H   = (unsigned short*)(ws);             // 12,845,056 B (fp16)
  float*  AS          = (float*)(ws + 12845056);           //    802,816 B
  float*  AD          = (float*)(ws + 13647872);           //    802,816 B
  unsigned short* X2  = (unsigned short*)(ws + 14450688);  // 12,845,056 B
  int2*   rpdeg       = (int2*)(ws + 27295744);            //    400,000 B
  unsigned short* csr = (unsigned short*)(ws + 27695744);  //  2,408,448 B (196*CAPC*2)
  unsigned int* ebuf  = (unsigned int*)(ws + 30104192);    //  3,612,672 B (196*CAP*4)
  int*    gcur        = (int*)(ws + 33716864);             //        784 B
  int*    flags       = (int*)(ws + 33718016);             //         64 B
  unsigned short* Wt1 = (unsigned short*)(ws + 33719040);  //     32,768 B
  unsigned short* Wt2 = (unsigned short*)(ws + 33751808);  //     32,768 B
  unsigned short* Ba1 = (unsigned short*)(ws + 33784576);  //      4,096 B
  unsigned short* Ba2 = (unsigned short*)(ws + 33788672);  //      4,096 B

  const int agg_blocks = (N_NODES + 7) / 8;                // 2 nodes per wave

  // prep: detect + W transpose + Ba + gcur init (fused, 1 launch)
  k_prep<<<264, 256, 0, stream>>>(W1, W2, as1, ad1, as2, ad2,
                                  Wt1, Wt2, Ba1, Ba2,
                                  (const unsigned short*)x,
                                  (const unsigned int*)ei, flags, gcur);

  // layer-1 GEMM overlapped with bucket scatter (single edge pass)
  k_gemm_scat<<<GEMMB + NEB, 256, 0, stream>>>(
      x, Wt1, Ba1, H, AS, AD, N_NODES, ei, gcur, ebuf, flags);

  // per-bucket fine CSR (aligned segments, pad-only zeroing)
  k_fine<<<NBUCK, 256, 0, stream>>>(ebuf, gcur, rpdeg, csr);

  // layer 1 aggregate
  k_agg<<<agg_blocks, 256, 0, stream>>>(rpdeg, csr, H, AS, AD,
                                        b1, X2, flags, 1);

  // layer 2
  k_gemm<<<GEMMB, 256, 0, stream>>>(X2, Wt2, Ba2, H, AS, AD, N_NODES);
  k_agg<<<agg_blocks, 256, 0, stream>>>(rpdeg, csr, H, AS, AD,
                                        b2, d_out, flags, 2);
}

// Round 11
// 193.984 us; speedup vs baseline: 1.0051x; 1.0051x over previous
//
#include <hip/hip_runtime.h>
#include <hip/hip_bf16.h>
#include <hip/hip_fp16.h>

#define N_NODES 50000
#define N_EDGES 640000
#define E_TOT   690000   // edges + self-loops
#define CH      128
#define ROWPAD  50176    // padded rows for H/AS/AD/X2 (128-row GEMM tiles overrun)
#define GEMMB   391      // ceil(50000 / 128) row-tiles of 128
#define EBLK    2048     // edges per scatter block
#define NEB     337      // ceil(E_TOT / EBLK)
#define NBUCK   196      // ceil(N_NODES / 256)
#define CAP     4608     // ebuf bucket capacity (mean 3533, sigma 57)
#define CAPC    6144     // csr bucket capacity (edges + 256 nodes x 7 align pad)

typedef __attribute__((ext_vector_type(8))) short short8;
typedef __attribute__((ext_vector_type(4))) float float4v;

static __device__ __forceinline__ float bf2f(unsigned short u) {
  return __uint_as_float(((unsigned)u) << 16);
}
static __device__ __forceinline__ unsigned short f2bf(float f) {
  unsigned u = __float_as_uint(f);
  return (unsigned short)((u + 0x7fffu + ((u >> 16) & 1u)) >> 16);
}

static __device__ __forceinline__ void load_edge(const int* __restrict__ ei,
                                                 int e, int i64, int& s, int& d)
{
  if (e >= N_EDGES) { s = d = e - N_EDGES; return; }
  if (i64) { s = ei[2 * (size_t)e]; d = ei[2 * ((size_t)N_EDGES + e)]; }
  else     { s = ei[e];             d = ei[N_EDGES + e]; }
}

static __device__ __forceinline__ short8 load_bf8(const void* __restrict__ X,
                                                  size_t off, int f32)
{
  if (!f32) return *(const short8*)((const unsigned short*)X + off);
  const float4* p = (const float4*)((const float*)X + off);
  float4 u = p[0], v = p[1];
  short8 r;
  r[0] = (short)f2bf(u.x); r[1] = (short)f2bf(u.y);
  r[2] = (short)f2bf(u.z); r[3] = (short)f2bf(u.w);
  r[4] = (short)f2bf(v.x); r[5] = (short)f2bf(v.y);
  r[6] = (short)f2bf(v.z); r[7] = (short)f2bf(v.w);
  return r;
}

// ---- prep: fused dtype-detect + W transpose + Ba + gcur init -----------
__global__ __launch_bounds__(256) void k_prep(
    const void* __restrict__ W1, const void* __restrict__ W2,
    const void* __restrict__ as1, const void* __restrict__ ad1,
    const void* __restrict__ as2, const void* __restrict__ ad2,
    unsigned short* __restrict__ Wt1, unsigned short* __restrict__ Wt2,
    unsigned short* __restrict__ Ba1, unsigned short* __restrict__ Ba2,
    const unsigned short* __restrict__ x16,
    const unsigned int* __restrict__ eiw,
    int* __restrict__ flags, int* __restrict__ gcur)
{
  int b = blockIdx.x, t = threadIdx.x;
  __shared__ int sf, si;
  if (t == 0) { sf = 0; si = 1; }
  __syncthreads();
  int bad = 0;
  for (int i = t; i < 4096; i += 256) {
    float v = bf2f(x16[i]);
    if (!(v == v) || fabsf(v) > 100.f) bad = 1;
  }
  if (bad) atomicOr(&sf, 1);
  if (b == 0 && t < 128 && eiw[2 * t + 1] != 0u) atomicAnd(&si, 0);
  __syncthreads();
  int f32 = sf;
  if (b == 0 && t == 0) { flags[0] = sf; flags[1] = si; }
  if (b == 0 && t < NBUCK) gcur[t] = t * CAP;   // re-init every launch

  if (b < 8) {
    int g = b * 256 + t;          // 0..2047
    int l = g >> 10;
    int rem = g & 1023;
    int k = rem >> 3, n = rem & 7;
    const void* W  = l ? W2 : W1;
    const void* av = (n < 4) ? (l ? as2 : as1) : (l ? ad2 : ad1);
    int h = n & 3;
    float sum = 0.f;
    for (int c = 0; c < 32; c++) {
      float w = f32 ? ((const float*)W)[k * 128 + h * 32 + c]
                    : bf2f(((const unsigned short*)W)[k * 128 + h * 32 + c]);
      float a = f32 ? ((const float*)av)[h * 32 + c]
                    : bf2f(((const unsigned short*)av)[h * 32 + c]);
      sum += w * a;
    }
    unsigned short* Ba = l ? Ba2 : Ba1;
    Ba[n * 128 + k] = f2bf(sum);
    Ba[(8 + (rem >> 7)) * 128 + (rem & 127)] = 0;   // zero rows 8..15
  } else {
    int b2 = b - 8;
    int l = b2 >> 7, c = b2 & 127;
    if (t < 128) {
      const void* W = l ? W2 : W1;
      unsigned short* Wt = l ? Wt2 : Wt1;
      Wt[c * 128 + t] = f32 ? f2bf(((const float*)W)[t * 128 + c])
                            : ((const unsigned short*)W)[t * 128 + c];
    }
  }
}

// ---- shared GEMM body: 128-row tiles, each B-frag feeds 2 MFMAs ---------
// SmemG = 39,168 B -> 4 blocks/CU fit in 160KB LDS; launch_bounds(256,4)
// (was (256,2): self-inflicted 2-block/CU cap on a latency-bound kernel).
struct SmemG { unsigned short WB[144][136]; };

static __device__ __forceinline__ void gemm_body(
    SmemG& sm, int bx,
    const void* __restrict__ X,
    const unsigned short* __restrict__ Wt_g,
    const unsigned short* __restrict__ Ba_g,
    unsigned short* __restrict__ H, float* __restrict__ AS,
    float* __restrict__ AD, int nrows, int xf32)
{
  int tid = threadIdx.x;
#pragma unroll
  for (int i = 0; i < 8; i++) {
    int j = i * 256 + tid;        // 2048 16B chunks of W^T
    int c = j >> 4, k8 = j & 15;
    *(short8*)&sm.WB[c][k8 * 8] = *(const short8*)(Wt_g + c * 128 + k8 * 8);
  }
  {
    int n = tid >> 4, k8 = tid & 15;   // Ba rows 128..143 (8..15 zeroed)
    *(short8*)&sm.WB[128 + n][k8 * 8] = *(const short8*)(Ba_g + n * 128 + k8 * 8);
  }
  __syncthreads();
  int wave = tid >> 6, lane = tid & 63;
  int R0 = (bx * 4 + wave) * 32;
  if (R0 >= nrows) return;
  int m = lane & 15, quad = lane >> 4;
  int rA = R0 + m;        if (rA >= nrows) rA = nrows - 1;   // clamp: last tile only
  int rB = R0 + 16 + m;   if (rB >= nrows) rB = nrows - 1;
  size_t aA = (size_t)rA * CH + quad * 8;
  size_t aB = (size_t)rB * CH + quad * 8;
  float4v acc[2][8];
  float4v accA[2];
#pragma unroll
  for (int hf = 0; hf < 2; hf++) {
    accA[hf] = (float4v){0.f, 0.f, 0.f, 0.f};
#pragma unroll
    for (int ct = 0; ct < 8; ct++) acc[hf][ct] = (float4v){0.f, 0.f, 0.f, 0.f};
  }
#pragma unroll
  for (int kb = 0; kb < 4; kb++) {
    short8 a0 = load_bf8(X, aA + kb * 32, xf32);
    short8 a1 = load_bf8(X, aB + kb * 32, xf32);
#pragma unroll
    for (int ct = 0; ct < 8; ct++) {
      short8 bb = *(const short8*)&sm.WB[ct * 16 + m][kb * 32 + quad * 8];
      acc[0][ct] = __builtin_amdgcn_mfma_f32_16x16x32_bf16(a0, bb, acc[0][ct], 0, 0, 0);
      acc[1][ct] = __builtin_amdgcn_mfma_f32_16x16x32_bf16(a1, bb, acc[1][ct], 0, 0, 0);
    }
    short8 bA = *(const short8*)&sm.WB[128 + m][kb * 32 + quad * 8];
    accA[0] = __builtin_amdgcn_mfma_f32_16x16x32_bf16(a0, bA, accA[0], 0, 0, 0);
    accA[1] = __builtin_amdgcn_mfma_f32_16x16x32_bf16(a1, bA, accA[1], 0, 0, 0);
  }
#pragma unroll
  for (int hf = 0; hf < 2; hf++) {
    int rbase = R0 + hf * 16 + quad * 4;
#pragma unroll
    for (int ct = 0; ct < 8; ct++) {
      int col = ct * 16 + m;
#pragma unroll
      for (int r = 0; r < 4; r++)
        H[(size_t)(rbase + r) * CH + col] = __half_as_ushort(__float2half(acc[hf][ct][r]));
    }
    if (m < 4) {
#pragma unroll
      for (int r = 0; r < 4; r++)
        AS[(size_t)(rbase + r) * 4 + m] = accA[hf][r];
    } else if (m < 8) {
#pragma unroll
      for (int r = 0; r < 4; r++)
        AD[(size_t)(rbase + r) * 4 + (m - 4)] = accA[hf][r];
    }
  }
}

// layer-2 GEMM (standalone; X2 always bf16)
__global__ __launch_bounds__(256, 4) void k_gemm(
    const void* __restrict__ X,
    const unsigned short* __restrict__ Wt_g,
    const unsigned short* __restrict__ Ba_g,
    unsigned short* __restrict__ H, float* __restrict__ AS, float* __restrict__ AD,
    int nrows)
{
  __shared__ SmemG sm;
  gemm_body(sm, blockIdx.x, X, Wt_g, Ba_g, H, AS, AD, nrows, 0);
}

// layer-1 GEMM fused with block-local counting-sort scatter.
// (round-1 lesson: per-node global cursors = 15x write amplification from
// cross-XCD line bouncing; ~10-edge contiguous chunks avoid that.)
__global__ __launch_bounds__(256, 4) void k_gemm_scat(
    const void* __restrict__ X,
    const unsigned short* __restrict__ Wt_g,
    const unsigned short* __restrict__ Ba_g,
    unsigned short* __restrict__ H, float* __restrict__ AS, float* __restrict__ AD,
    int nrows, const int* __restrict__ ei, int* __restrict__ gcur,
    unsigned int* __restrict__ ebuf, const int* __restrict__ flags)
{
  __shared__ SmemG sm;          // gemm blocks only
  __shared__ int hist[NBUCK];   // scatter blocks only
  __shared__ int cur[NBUCK];
  if (blockIdx.x >= GEMMB) {
    int b = blockIdx.x - GEMMB;
    int t = threadIdx.x;
    if (t < NBUCK) hist[t] = 0;
    __syncthreads();
    int i64 = flags[1];
    int base = b * EBLK;
    int sA[8], dA[8];
#pragma unroll
    for (int k = 0; k < 8; k++) {
      int e = base + k * 256 + t;
      sA[k] = -1;
      if (e < E_TOT) {
        load_edge(ei, e, i64, sA[k], dA[k]);
        atomicAdd(&hist[dA[k] >> 8], 1);
      }
    }
    __syncthreads();
    if (t < NBUCK) {
      int c = hist[t];
      cur[t] = c ? atomicAdd(&gcur[t], c) : 0;   // reserve contiguous chunk
    }
    __syncthreads();
#pragma unroll
    for (int k = 0; k < 8; k++) {
      if (sA[k] >= 0) {
        int pos = atomicAdd(&cur[dA[k] >> 8], 1);   // LDS atomic
        ebuf[pos] = ((unsigned)sA[k] << 8) | (unsigned)(dA[k] & 255);
      }
    }
    return;
  }
  gemm_body(sm, blockIdx.x, X, Wt_g, Ba_g, H, AS, AD, nrows, flags[0]);
}

// per-bucket fine CSR -> rpdeg (int2) + ushort csr.
// 8-entry-aligned segments so k_agg fetches 8 indices with one short8;
// only the pad slots are zeroed (<=7/node) — agg reads stay inside segments.
__global__ __launch_bounds__(256) void k_fine(
    const unsigned int* __restrict__ ebuf, const int* __restrict__ gcur,
    int2* __restrict__ rpdeg, unsigned short* __restrict__ csr)
{
  __shared__ int cnt[256], sh[256], cur[256];
  int q = blockIdx.x, t = threadIdx.x;
  int lo = q * CAP, hi = gcur[q];
  int lc = q * CAPC;
  cnt[t] = 0;
  __syncthreads();
  for (int i = lo + t; i < hi; i += 256)
    atomicAdd(&cnt[ebuf[i] & 255u], 1);
  __syncthreads();
  int v = cnt[t];
  int a = (v + 7) & ~7;          // 8-aligned segment size
  sh[t] = a;
  __syncthreads();
  for (int off = 1; off < 256; off <<= 1) {
    int u = (t >= off) ? sh[t - off] : 0;
    __syncthreads();
    sh[t] += u;
    __syncthreads();
  }
  int lpa = sh[t] - a;           // exclusive aligned prefix
  int n = (q << 8) + t;
  if (n < N_NODES) rpdeg[n] = make_int2(lc + lpa, v);
  cur[t] = lc + lpa;
  for (int i = v; i < a; i++) csr[lc + lpa + i] = 0;   // zero pad slots only
  __syncthreads();
  for (int i = lo + t; i < hi; i += 256) {
    unsigned p = ebuf[i];
    int slot = atomicAdd(&cur[p & 255u], 1);   // LDS atomic
    csr[slot] = (unsigned short)(p >> 8);
  }
}

// ---- fused gather-aggregate + softmax + epilogue ------------------------
// two nodes per wave (32 lanes/node, 4 ch/lane); one short8 csr load per
// 8-edge round, software-pipelined. At the random-gather floor (~7 TB/s
// effective from L3) — do not micro-optimize further (rounds 9/10 neutral).
__global__ __launch_bounds__(256, 8) void k_agg(
    const int2* __restrict__ rpdeg,
    const unsigned short* __restrict__ csr,
    const unsigned short* __restrict__ H,
    const float* __restrict__ AS, const float* __restrict__ AD,
    const void* __restrict__ b, void* __restrict__ Y,
    const int* __restrict__ flags, int layer)
{
  int tid = threadIdx.x;
  int node = blockIdx.x * 8 + (tid >> 5);
  if (node >= N_NODES) return;
  int lane = tid & 31;
  int h = lane >> 3;          // 4 channels/lane
  int c0 = 4 * lane;
  int2 rd = rpdeg[node];
  int start = rd.x, dg = rd.y;
  float adh = AD[node * 4 + h];
  float acc0 = 0.f, acc1 = 0.f, acc2 = 0.f, acc3 = 0.f, den = 0.f;
  int nr = (dg + 7) >> 3;                          // rounds (dg >= 1)
  short8 sv = *(const short8*)(csr + start);       // preload round 0
  for (int r = 0; r < nr; r++) {
    int jn = (r + 1 < nr) ? (r + 1) * 8 : r * 8;   // clamp: dup last (in-bounds)
    short8 svn = *(const short8*)(csr + start + jn);   // prefetch next round
    int j = r * 8;
    int sI[8];
#pragma unroll
    for (int u = 0; u < 8; u++) sI[u] = ((int)sv[u]) & 0xFFFF;
    float2 vR[8];
#pragma unroll
    for (int u = 0; u < 8; u++)
      vR[u] = *(const float2*)(H + (sI[u] << 7) + c0);   // 4 halves, 8B
    float eV[8];
#pragma unroll
    for (int u = 0; u < 8; u++)
      eV[u] = AS[(sI[u] << 2) + h] + adh;
#pragma unroll
    for (int u = 0; u < 8; u++) {
      float x = eV[u];
      x = fmaxf(x, 0.2f * x);                  // leaky_relu(0.2)
      float ex = (j + u < dg) ? __expf(x) : 0.f;
      __half2 p0 = __builtin_bit_cast(__half2, vR[u].x);
      __half2 p1 = __builtin_bit_cast(__half2, vR[u].y);
      float2 f0 = __half22float2(p0);
      float2 f1 = __half22float2(p1);
      acc0 += ex * f0.x;
      acc1 += ex * f0.y;
      acc2 += ex * f1.x;
      acc3 += ex * f1.y;
      den  += ex;
    }
    sv = svn;
  }
  float inv = 1.f / (den + 1e-16f);
  int f32 = flags[0];
  float b0, b1, b2, b3;
  if (f32) {
    const float* bp = (const float*)b;
    b0 = bp[c0]; b1 = bp[c0 + 1]; b2 = bp[c0 + 2]; b3 = bp[c0 + 3];
  } else {
    const unsigned short* bp = (const unsigned short*)b;
    b0 = bf2f(bp[c0]); b1 = bf2f(bp[c0 + 1]);
    b2 = bf2f(bp[c0 + 2]); b3 = bf2f(bp[c0 + 3]);
  }
  float r0 = acc0 * inv + b0;
  float r1 = acc1 * inv + b1;
  float r2 = acc2 * inv + b2;
  float r3 = acc3 * inv + b3;
  int o = node * CH + c0;
  if (layer == 1) {                 // relu + bf16 -> X2
    r0 = r0 > 0.f ? r0 : 0.f;  r1 = r1 > 0.f ? r1 : 0.f;
    r2 = r2 > 0.f ? r2 : 0.f;  r3 = r3 > 0.f ? r3 : 0.f;
    ushort4 w;
    w.x = f2bf(r0); w.y = f2bf(r1); w.z = f2bf(r2); w.w = f2bf(r3);
    *(ushort4*)((unsigned short*)Y + o) = w;
  } else if (f32) {
    float4 w; w.x = r0; w.y = r1; w.z = r2; w.w = r3;
    *(float4*)((float*)Y + o) = w;
  } else {
    ushort4 w;
    w.x = f2bf(r0); w.y = f2bf(r1); w.z = f2bf(r2); w.w = f2bf(r3);
    *(ushort4*)((unsigned short*)Y + o) = w;
  }
}

extern "C" void kernel_launch(void* const* d_in, const int* in_sizes, int n_in,
                              void* d_out, int out_size, void* d_ws, size_t ws_size,
                              hipStream_t stream)
{
  const void* x   = d_in[0];
  const int*  ei  = (const int*)d_in[1];
  const void* W1  = d_in[2];
  const void* as1 = d_in[3];
  const void* ad1 = d_in[4];
  const void* b1  = d_in[5];
  const void* W2  = d_in[6];
  const void* as2 = d_in[7];
  const void* ad2 = d_in[8];
  const void* b2  = d_in[9];

  char* ws = (char*)d_ws;
  unsigned short* H   = (unsigned short*)(ws);             // 12,845,056 B (fp16)
  float*  AS          = (float*)(ws + 12845056);           //    802,816 B
  float*  AD          = (float*)(ws + 13647872);           //    802,816 B
  unsigned short* X2  = (unsigned short*)(ws + 14450688);  // 12,845,056 B
  int2*   rpdeg       = (int2*)(ws + 27295744);            //    400,000 B
  unsigned short* csr = (unsigned short*)(ws + 27695744);  //  2,408,448 B (196*CAPC*2)
  unsigned int* ebuf  = (unsigned int*)(ws + 30104192);    //  3,612,672 B (196*CAP*4)
  int*    gcur        = (int*)(ws + 33716864);             //        784 B
  int*    flags       = (int*)(ws + 33718016);             //         64 B
  unsigned short* Wt1 = (unsigned short*)(ws + 33719040);  //     32,768 B
  unsigned short* Wt2 = (unsigned short*)(ws + 33751808);  //     32,768 B
  unsigned short* Ba1 = (unsigned short*)(ws + 33784576);  //      4,096 B
  unsigned short* Ba2 = (unsigned short*)(ws + 33788672);  //      4,096 B

  const int agg_blocks = (N_NODES + 7) / 8;                // 2 nodes per wave

  // prep: detect + W transpose + Ba + gcur init (fused, 1 launch)
  k_prep<<<264, 256, 0, stream>>>(W1, W2, as1, ad1, as2, ad2,
                                  Wt1, Wt2, Ba1, Ba2,
                                  (const unsigned short*)x,
                                  (const unsigned int*)ei, flags, gcur);

  // layer-1 GEMM overlapped with bucket scatter (single edge pass)
  k_gemm_scat<<<GEMMB + NEB, 256, 0, stream>>>(
      x, Wt1, Ba1, H, AS, AD, N_NODES, ei, gcur, ebuf, flags);

  // per-bucket fine CSR (aligned segments, pad-only zeroing)
  k_fine<<<NBUCK, 256, 0, stream>>>(ebuf, gcur, rpdeg, csr);

  // layer 1 aggregate
  k_agg<<<agg_blocks, 256, 0, stream>>>(rpdeg, csr, H, AS, AD,
                                        b1, X2, flags, 1);

  // layer 2
  k_gemm<<<GEMMB, 256, 0, stream>>>(X2, Wt2, Ba2, H, AS, AD, N_NODES);
  k_agg<<<agg_blocks, 256, 0, stream>>>(rpdeg, csr, H, AS, AD,
                                        b2, d_out, flags, 2);
}